// Round 3
// baseline (1307.481 us; speedup 1.0000x reference)
//
#include <hip/hip_runtime.h>

#define IN_DIM 1024
#define HID 32
#define BSHIFT 5            // 32 rows per bucket
#define BROWS 32
#define MAXB 1600           // max buckets (N up to 51200)
#define NBLK 64             // partition blocks

__device__ __forceinline__ float selu_f(float x) {
    const float scale = 1.0507009873554805f;
    const float alpha = 1.6732632423543772f;
    return x > 0.f ? scale * x : scale * alpha * (expf(x) - 1.f);
}

// ---------------- Bucket partition (replaces per-row CSR) ----------------
// counts[b*NBLK + blk] = #edges of bucket b in block blk's chunk. All entries written.

__global__ __launch_bounds__(1024) void part_hist(const int* __restrict__ rows, int E, int NB,
                                                  int nchunk, int* __restrict__ counts) {
    __shared__ int lh[MAXB];
    int tid = threadIdx.x, blk = blockIdx.x;
    for (int b = tid; b < NB; b += 1024) lh[b] = 0;
    __syncthreads();
    int base = blk * nchunk;
    int end = base + nchunk; if (end > E) end = E;
    for (int i = base + tid; i < end; i += 1024)
        atomicAdd(&lh[rows[i] >> BSHIFT], 1);
    __syncthreads();
    for (int b = tid; b < NB; b += 1024) counts[b * NBLK + blk] = lh[b];
}

// exclusive scan of n<=128K elements: per-block scan + block-partials fixup
__global__ __launch_bounds__(1024) void scan1_kernel(const int* __restrict__ in, int n,
                                                     int* __restrict__ out,
                                                     int* __restrict__ partials) {
    __shared__ int s[1024];
    int tid = threadIdx.x;
    int i = blockIdx.x * 1024 + tid;
    int v = (i < n) ? in[i] : 0;
    s[tid] = v;
    __syncthreads();
    for (int off = 1; off < 1024; off <<= 1) {
        int t = (tid >= off) ? s[tid - off] : 0;
        __syncthreads();
        s[tid] += t;
        __syncthreads();
    }
    if (i < n) out[i] = s[tid] - v;            // exclusive within block
    if (tid == 1023) partials[blockIdx.x] = s[tid];
}

__global__ void scan2_kernel(int* __restrict__ partials, int nb) {  // nb <= 128, 1 block
    __shared__ int s[128];
    int tid = threadIdx.x;
    int v = (tid < nb) ? partials[tid] : 0;
    s[tid] = v;
    __syncthreads();
    for (int off = 1; off < 128; off <<= 1) {
        int t = (tid >= off) ? s[tid - off] : 0;
        __syncthreads();
        s[tid] += t;
        __syncthreads();
    }
    if (tid < nb) partials[tid] = s[tid] - v;  // exclusive block offsets
}

__global__ __launch_bounds__(1024) void scan3_kernel(int* __restrict__ out,
                                                     const int* __restrict__ partials, int n) {
    int i = blockIdx.x * 1024 + threadIdx.x;
    if (i < n) out[i] += partials[blockIdx.x];
}

// Scatter with LDS cursors: positions deterministic per (bucket,block) segment (~16 edges
// = 128B contiguous) -> near-line-granular writes, zero global atomics.
__global__ __launch_bounds__(1024) void part_scatter(const int* __restrict__ rows,
                                                     const int* __restrict__ cols,
                                                     const float* __restrict__ vals, int E,
                                                     int NB, int nchunk,
                                                     const int* __restrict__ offs,
                                                     int2* __restrict__ edata) {
    __shared__ int lc[MAXB];
    int tid = threadIdx.x, blk = blockIdx.x;
    for (int b = tid; b < NB; b += 1024) lc[b] = offs[b * NBLK + blk];
    __syncthreads();
    int base = blk * nchunk;
    int end = base + nchunk; if (end > E) end = E;
    for (int i = base + tid; i < end; i += 1024) {
        int r = rows[i];
        int b = r >> BSHIFT;
        int p = atomicAdd(&lc[b], 1);
        int2 pr;
        pr.x = ((r & (BROWS - 1)) << 18) | cols[i];   // rl:5b | col:18b
        pr.y = __float_as_int(vals[i]);
        edata[p] = pr;
    }
}

// ---------------- GEMM1: support1 = x @ w1  (fp32, memory-bound on x) ----------------

#define XS_LD 132

__global__ __launch_bounds__(256) void gemm1_kernel(const float* __restrict__ x,
                                                    const float* __restrict__ w,
                                                    float* __restrict__ out, int N) {
    __shared__ float xs[32 * XS_LD];
    __shared__ float ws[128 * HID];
    int tid = threadIdx.x;
    int r  = tid >> 3;
    int d0 = (tid & 7) * 4;
    int row0 = blockIdx.x * 32;

    float4 acc = make_float4(0.f, 0.f, 0.f, 0.f);

    for (int kc = 0; kc < IN_DIM; kc += 128) {
        #pragma unroll
        for (int j = 0; j < 4; ++j) {
            int linear = tid + j * 256;
            int rr = linear >> 5;
            int cc = linear & 31;
            int grow = row0 + rr;
            if (grow > N - 1) grow = N - 1;
            float4 t = *(const float4*)&x[(size_t)grow * IN_DIM + kc + cc * 4];
            *(float4*)&xs[rr * XS_LD + cc * 4] = t;
        }
        #pragma unroll
        for (int j = 0; j < 4; ++j) {
            int linear = tid + j * 256;
            int kk = linear >> 3;
            int dd = (linear & 7) * 4;
            float4 t = *(const float4*)&w[(kc + kk) * HID + dd];
            *(float4*)&ws[kk * HID + dd] = t;
        }
        __syncthreads();
        #pragma unroll
        for (int k4 = 0; k4 < 32; ++k4) {
            float4 xv = *(const float4*)&xs[r * XS_LD + k4 * 4];
            float4 wv0 = *(const float4*)&ws[(k4 * 4 + 0) * HID + d0];
            acc.x += xv.x * wv0.x; acc.y += xv.x * wv0.y; acc.z += xv.x * wv0.z; acc.w += xv.x * wv0.w;
            float4 wv1 = *(const float4*)&ws[(k4 * 4 + 1) * HID + d0];
            acc.x += xv.y * wv1.x; acc.y += xv.y * wv1.y; acc.z += xv.y * wv1.z; acc.w += xv.y * wv1.w;
            float4 wv2 = *(const float4*)&ws[(k4 * 4 + 2) * HID + d0];
            acc.x += xv.z * wv2.x; acc.y += xv.z * wv2.y; acc.z += xv.z * wv2.z; acc.w += xv.z * wv2.w;
            float4 wv3 = *(const float4*)&ws[(k4 * 4 + 3) * HID + d0];
            acc.x += xv.w * wv3.x; acc.y += xv.w * wv3.y; acc.z += xv.w * wv3.z; acc.w += xv.w * wv3.w;
        }
        __syncthreads();
    }
    int grow = row0 + r;
    if (grow < N) *(float4*)&out[(size_t)grow * HID + d0] = acc;
}

// ---------------- Bucketed SpMM: one block per 32-row bucket ----------------
// LDS acc[32][33]; 32-lane teams, one edge per team-iter: broadcast edata load,
// 128B coalesced gather of sup[col][:], ds_add_f32 accumulate.

__device__ __forceinline__ void bucket_accumulate(const float* __restrict__ sup,
                                                  const int2* __restrict__ edata,
                                                  int s0, int s1, int team, int d,
                                                  float (*acc)[33]) {
    int e = s0 + team;
    for (; e + 8 < s1; e += 16) {           // 2 edges in flight per team
        int2 p0 = edata[e];
        int2 p1 = edata[e + 8];
        float g0 = sup[(p0.x & 0x3FFFF) * HID + d];
        float g1 = sup[(p1.x & 0x3FFFF) * HID + d];
        atomicAdd(&acc[p0.x >> 18][d], __int_as_float(p0.y) * g0);
        atomicAdd(&acc[p1.x >> 18][d], __int_as_float(p1.y) * g1);
    }
    for (; e < s1; e += 8) {
        int2 p0 = edata[e];
        float g0 = sup[(p0.x & 0x3FFFF) * HID + d];
        atomicAdd(&acc[p0.x >> 18][d], __int_as_float(p0.y) * g0);
    }
}

__global__ __launch_bounds__(256) void spmm_mid_kernel(const float* __restrict__ sup,
                                                       const int* __restrict__ offs,
                                                       const int2* __restrict__ edata,
                                                       int E, int N, int NB,
                                                       const float* __restrict__ bias,
                                                       const float* __restrict__ Wn,
                                                       float* __restrict__ out) {
    __shared__ float Wsh[HID * HID];
    __shared__ float acc[BROWS][33];
    __shared__ float hs[BROWS][33];
    int tid = threadIdx.x;
    int b = blockIdx.x;
    *(float4*)&Wsh[tid * 4] = *(const float4*)&Wn[tid * 4];
    for (int i = tid; i < BROWS * 33; i += 256) ((float*)acc)[i] = 0.f;
    __syncthreads();

    int s0 = offs[b * NBLK];
    int s1 = (b + 1 < NB) ? offs[(b + 1) * NBLK] : E;
    int team = tid >> 5, d = tid & 31;
    bucket_accumulate(sup, edata, s0, s1, team, d, acc);
    __syncthreads();

    float bd = bias[d];
    #pragma unroll
    for (int k = 0; k < 4; ++k) {
        int rl = (tid >> 5) + k * 8;
        hs[rl][d] = selu_f(acc[rl][d]) + bd;
    }
    __syncthreads();
    #pragma unroll
    for (int k = 0; k < 4; ++k) {
        int rl = (tid >> 5) + k * 8;
        int row = b * BROWS + rl;
        float o = 0.f;
        #pragma unroll
        for (int j = 0; j < HID; ++j) o += hs[rl][j] * Wsh[j * HID + d];
        if (row < N) out[(size_t)row * HID + d] = o;
    }
}

__global__ __launch_bounds__(256) void spmm_final_kernel(const float* __restrict__ sup,
                                                         const int* __restrict__ offs,
                                                         const int2* __restrict__ edata,
                                                         int E, int N, int NB,
                                                         const float* __restrict__ bias,
                                                         const float* __restrict__ cw0,
                                                         const float* __restrict__ cb0,
                                                         const float* __restrict__ cw1,
                                                         const float* __restrict__ cb1,
                                                         float* __restrict__ out) {
    __shared__ float acc[BROWS][33];
    __shared__ float hs[BROWS][33];
    int tid = threadIdx.x;
    int b = blockIdx.x;
    for (int i = tid; i < BROWS * 33; i += 256) ((float*)acc)[i] = 0.f;
    __syncthreads();

    int s0 = offs[b * NBLK];
    int s1 = (b + 1 < NB) ? offs[(b + 1) * NBLK] : E;
    int team = tid >> 5, d = tid & 31;
    bucket_accumulate(sup, edata, s0, s1, team, d, acc);
    __syncthreads();

    float bd = bias[d];
    #pragma unroll
    for (int k = 0; k < 4; ++k) {
        int rl = (tid >> 5) + k * 8;
        hs[rl][d] = selu_f(acc[rl][d]) + bd;
    }
    __syncthreads();
    if (tid < BROWS * 5) {
        int rl = tid / 5, t = tid % 5;
        int row = b * BROWS + rl;
        if (row < N) {
            if (t < 2) {
                float o = cb0[t];
                #pragma unroll
                for (int j = 0; j < HID; ++j) o += hs[rl][j] * cw0[t * HID + j];
                out[(size_t)row * 2 + t] = o;
            } else {
                int c = t - 2;
                float o = cb1[c];
                #pragma unroll
                for (int j = 0; j < HID; ++j) o += hs[rl][j] * cw1[c * HID + j];
                out[(size_t)N * 2 + (size_t)row * 3 + c] = o;
            }
        }
    }
}

// ---------------- launch ----------------

extern "C" void kernel_launch(void* const* d_in, const int* in_sizes, int n_in,
                              void* d_out, int out_size, void* d_ws, size_t ws_size,
                              hipStream_t stream) {
    const float* x        = (const float*)d_in[0];
    const int*   adj_rows = (const int*)d_in[1];
    const int*   adj_cols = (const int*)d_in[2];
    const float* adj_vals = (const float*)d_in[3];
    const float* w1 = (const float*)d_in[4];
    const float* b1 = (const float*)d_in[5];
    const float* w2 = (const float*)d_in[6];
    const float* b2 = (const float*)d_in[7];
    const float* w3 = (const float*)d_in[8];
    const float* b3 = (const float*)d_in[9];
    const float* cw0 = (const float*)d_in[10];
    const float* cb0 = (const float*)d_in[11];
    const float* cw1 = (const float*)d_in[12];
    const float* cb1 = (const float*)d_in[13];

    int N = in_sizes[0] / IN_DIM;   // 50000
    int E = in_sizes[1];            // 1.6M
    int NB = (N + BROWS - 1) >> BSHIFT;      // 1563 buckets
    int M = NB * NBLK;                        // counts matrix size (~100K)
    int nchunk = (E + NBLK - 1) / NBLK;       // 25000 edges per partition block
    int nb1 = (M + 1023) / 1024;              // scan blocks (98 <= 128)

    char* p = (char*)d_ws;
    float* s_a   = (float*)p; p += (size_t)N * HID * sizeof(float);
    float* s_b   = (float*)p; p += (size_t)N * HID * sizeof(float);
    int2*  edata = (int2*)p;  p += (size_t)E * sizeof(int2);
    int*   counts   = (int*)p; p += (size_t)M * sizeof(int);
    int*   offs     = (int*)p; p += (size_t)M * sizeof(int);
    int*   partials = (int*)p; p += 128 * sizeof(int);

    // Bucket partition (once per call; reused by all 3 SpMM layers)
    part_hist<<<NBLK, 1024, 0, stream>>>(adj_rows, E, NB, nchunk, counts);
    scan1_kernel<<<nb1, 1024, 0, stream>>>(counts, M, offs, partials);
    scan2_kernel<<<1, 128, 0, stream>>>(partials, nb1);
    scan3_kernel<<<nb1, 1024, 0, stream>>>(offs, partials, M);
    part_scatter<<<NBLK, 1024, 0, stream>>>(adj_rows, adj_cols, adj_vals, E, NB, nchunk,
                                            offs, edata);

    // Layer pipeline
    gemm1_kernel<<<(N + 31) / 32, 256, 0, stream>>>(x, w1, s_a, N);
    spmm_mid_kernel<<<NB, 256, 0, stream>>>(s_a, offs, edata, E, N, NB, b1, w2, s_b);
    spmm_mid_kernel<<<NB, 256, 0, stream>>>(s_b, offs, edata, E, N, NB, b2, w3, s_a);
    spmm_final_kernel<<<NB, 256, 0, stream>>>(s_a, offs, edata, E, N, NB,
                                              b3, cw0, cb0, cw1, cb1, (float*)d_out);
}

// Round 4
// 496.089 us; speedup vs baseline: 2.6356x; 2.6356x over previous
//
#include <hip/hip_runtime.h>

#define IN_DIM 1024
#define HID 32
#define BSHIFT 5            // 32 rows per bucket
#define BROWS 32
#define MAXB 1600           // max buckets (N up to 51200)
#define NBLK 64             // partition blocks
#define SORT_CAP 4096       // bucket sort LDS capacity (edges); lambda=1024, 96-sigma safe

__device__ __forceinline__ float selu_f(float x) {
    const float scale = 1.0507009873554805f;
    const float alpha = 1.6732632423543772f;
    return x > 0.f ? scale * x : scale * alpha * (expf(x) - 1.f);
}

// ---------------- Bucket partition ----------------
// counts[b*NBLK + blk] = #edges of bucket b in block blk's chunk.

__global__ __launch_bounds__(1024) void part_hist(const int* __restrict__ rows, int E, int NB,
                                                  int nchunk, int* __restrict__ counts) {
    __shared__ int lh[MAXB];
    int tid = threadIdx.x, blk = blockIdx.x;
    for (int b = tid; b < NB; b += 1024) lh[b] = 0;
    __syncthreads();
    int base = blk * nchunk;
    int end = base + nchunk; if (end > E) end = E;
    for (int i = base + tid; i < end; i += 1024)
        atomicAdd(&lh[rows[i] >> BSHIFT], 1);
    __syncthreads();
    for (int b = tid; b < NB; b += 1024) counts[b * NBLK + blk] = lh[b];
}

__global__ __launch_bounds__(1024) void scan1_kernel(const int* __restrict__ in, int n,
                                                     int* __restrict__ out,
                                                     int* __restrict__ partials) {
    __shared__ int s[1024];
    int tid = threadIdx.x;
    int i = blockIdx.x * 1024 + tid;
    int v = (i < n) ? in[i] : 0;
    s[tid] = v;
    __syncthreads();
    for (int off = 1; off < 1024; off <<= 1) {
        int t = (tid >= off) ? s[tid - off] : 0;
        __syncthreads();
        s[tid] += t;
        __syncthreads();
    }
    if (i < n) out[i] = s[tid] - v;
    if (tid == 1023) partials[blockIdx.x] = s[tid];
}

__global__ void scan2_kernel(int* __restrict__ partials, int nb) {  // nb <= 128, 1 block
    __shared__ int s[128];
    int tid = threadIdx.x;
    int v = (tid < nb) ? partials[tid] : 0;
    s[tid] = v;
    __syncthreads();
    for (int off = 1; off < 128; off <<= 1) {
        int t = (tid >= off) ? s[tid - off] : 0;
        __syncthreads();
        s[tid] += t;
        __syncthreads();
    }
    if (tid < nb) partials[tid] = s[tid] - v;
}

__global__ __launch_bounds__(1024) void scan3_kernel(int* __restrict__ out,
                                                     const int* __restrict__ partials, int n) {
    int i = blockIdx.x * 1024 + threadIdx.x;
    if (i < n) out[i] += partials[blockIdx.x];
}

// LDS-cursor scatter into bucket segments (near-line-granular writes, no global atomics)
__global__ __launch_bounds__(1024) void part_scatter(const int* __restrict__ rows,
                                                     const int* __restrict__ cols,
                                                     const float* __restrict__ vals, int E,
                                                     int NB, int nchunk,
                                                     const int* __restrict__ offs,
                                                     int2* __restrict__ edata) {
    __shared__ int lc[MAXB];
    int tid = threadIdx.x, blk = blockIdx.x;
    for (int b = tid; b < NB; b += 1024) lc[b] = offs[b * NBLK + blk];
    __syncthreads();
    int base = blk * nchunk;
    int end = base + nchunk; if (end > E) end = E;
    for (int i = base + tid; i < end; i += 1024) {
        int r = rows[i];
        int b = r >> BSHIFT;
        int p = atomicAdd(&lc[b], 1);
        int2 pr;
        pr.x = ((r & (BROWS - 1)) << 18) | cols[i];   // rl:5b | col:18b (col < 2^18)
        pr.y = __float_as_int(vals[i]);
        edata[p] = pr;
    }
}

// In-place counting sort of each bucket by local row; emits rowptr.
__global__ __launch_bounds__(256) void bucket_sort(int2* __restrict__ edata,
                                                   const int* __restrict__ offs,
                                                   int E, int NB,
                                                   int* __restrict__ rowptr) {
    __shared__ int2 stage[SORT_CAP];
    __shared__ int cnt[32], startsh[32], cur[32];
    int b = blockIdx.x, tid = threadIdx.x;
    int s0 = offs[b * NBLK];
    int s1 = (b + 1 < NB) ? offs[(b + 1) * NBLK] : E;
    int n = s1 - s0;                       // ~1024; SORT_CAP is 96-sigma headroom
    if (tid < 32) cnt[tid] = 0;
    __syncthreads();
    for (int i = tid; i < n; i += 256) {
        int2 pr = edata[s0 + i];
        stage[i] = pr;
        atomicAdd(&cnt[pr.x >> 18], 1);
    }
    __syncthreads();
    if (tid == 0) {
        int run = 0;
        #pragma unroll
        for (int k = 0; k < 32; ++k) { startsh[k] = run; run += cnt[k]; }
    }
    __syncthreads();
    if (tid < 32) {
        cur[tid] = startsh[tid];
        rowptr[b * BROWS + tid] = s0 + startsh[tid];
    }
    __syncthreads();
    for (int i = tid; i < n; i += 256) {
        int2 pr = stage[i];
        int p = atomicAdd(&cur[pr.x >> 18], 1);
        edata[s0 + p] = pr;     // scattered only within this bucket's ~8KB window
    }
}

// ---------------- GEMM1: support1 = x @ w1 ----------------

#define XS_LD 132

__global__ __launch_bounds__(256) void gemm1_kernel(const float* __restrict__ x,
                                                    const float* __restrict__ w,
                                                    float* __restrict__ out, int N) {
    __shared__ float xs[32 * XS_LD];
    __shared__ float ws[128 * HID];
    int tid = threadIdx.x;
    int r  = tid >> 3;
    int d0 = (tid & 7) * 4;
    int row0 = blockIdx.x * 32;

    float4 acc = make_float4(0.f, 0.f, 0.f, 0.f);

    for (int kc = 0; kc < IN_DIM; kc += 128) {
        #pragma unroll
        for (int j = 0; j < 4; ++j) {
            int linear = tid + j * 256;
            int rr = linear >> 5;
            int cc = linear & 31;
            int grow = row0 + rr;
            if (grow > N - 1) grow = N - 1;
            float4 t = *(const float4*)&x[(size_t)grow * IN_DIM + kc + cc * 4];
            *(float4*)&xs[rr * XS_LD + cc * 4] = t;
        }
        #pragma unroll
        for (int j = 0; j < 4; ++j) {
            int linear = tid + j * 256;
            int kk = linear >> 3;
            int dd = (linear & 7) * 4;
            float4 t = *(const float4*)&w[(kc + kk) * HID + dd];
            *(float4*)&ws[kk * HID + dd] = t;
        }
        __syncthreads();
        #pragma unroll
        for (int k4 = 0; k4 < 32; ++k4) {
            float4 xv = *(const float4*)&xs[r * XS_LD + k4 * 4];
            float4 wv0 = *(const float4*)&ws[(k4 * 4 + 0) * HID + d0];
            acc.x += xv.x * wv0.x; acc.y += xv.x * wv0.y; acc.z += xv.x * wv0.z; acc.w += xv.x * wv0.w;
            float4 wv1 = *(const float4*)&ws[(k4 * 4 + 1) * HID + d0];
            acc.x += xv.y * wv1.x; acc.y += xv.y * wv1.y; acc.z += xv.y * wv1.z; acc.w += xv.y * wv1.w;
            float4 wv2 = *(const float4*)&ws[(k4 * 4 + 2) * HID + d0];
            acc.x += xv.z * wv2.x; acc.y += xv.z * wv2.y; acc.z += xv.z * wv2.z; acc.w += xv.z * wv2.w;
            float4 wv3 = *(const float4*)&ws[(k4 * 4 + 3) * HID + d0];
            acc.x += xv.w * wv3.x; acc.y += xv.w * wv3.y; acc.z += xv.w * wv3.z; acc.w += xv.w * wv3.w;
        }
        __syncthreads();
    }
    int grow = row0 + r;
    if (grow < N) *(float4*)&out[(size_t)grow * HID + d0] = acc;
}

// ---------------- SpMM: 8-lane group per row, float4 register accumulator ----------------
// Per edge: broadcast 8B meta load + one 128B coalesced gather + 4 FMAs. No atomics/shfl.

__device__ __forceinline__ float4 spmm_row_f4(const float4* __restrict__ sup4,
                                              const int2* __restrict__ edata,
                                              int e0, int e1, int l) {
    float4 a0 = {0.f,0.f,0.f,0.f}, a1 = a0, a2 = a0, a3 = a0;
    int e = e0;
    for (; e + 4 <= e1; e += 4) {
        int2 m0 = edata[e], m1 = edata[e+1], m2 = edata[e+2], m3 = edata[e+3];
        float4 g0 = sup4[(size_t)(m0.x & 0x3FFFF) * 8 + l];
        float4 g1 = sup4[(size_t)(m1.x & 0x3FFFF) * 8 + l];
        float4 g2 = sup4[(size_t)(m2.x & 0x3FFFF) * 8 + l];
        float4 g3 = sup4[(size_t)(m3.x & 0x3FFFF) * 8 + l];
        float v0 = __int_as_float(m0.y), v1 = __int_as_float(m1.y);
        float v2 = __int_as_float(m2.y), v3 = __int_as_float(m3.y);
        a0.x += v0*g0.x; a0.y += v0*g0.y; a0.z += v0*g0.z; a0.w += v0*g0.w;
        a1.x += v1*g1.x; a1.y += v1*g1.y; a1.z += v1*g1.z; a1.w += v1*g1.w;
        a2.x += v2*g2.x; a2.y += v2*g2.y; a2.z += v2*g2.z; a2.w += v2*g2.w;
        a3.x += v3*g3.x; a3.y += v3*g3.y; a3.z += v3*g3.z; a3.w += v3*g3.w;
    }
    for (; e < e1; ++e) {
        int2 m0 = edata[e];
        float4 g0 = sup4[(size_t)(m0.x & 0x3FFFF) * 8 + l];
        float v0 = __int_as_float(m0.y);
        a0.x += v0*g0.x; a0.y += v0*g0.y; a0.z += v0*g0.z; a0.w += v0*g0.w;
    }
    a0.x += a1.x + a2.x + a3.x;
    a0.y += a1.y + a2.y + a3.y;
    a0.z += a1.z + a2.z + a3.z;
    a0.w += a1.w + a2.w + a3.w;
    return a0;
}

__global__ __launch_bounds__(256) void spmm_mid_kernel(const float4* __restrict__ sup4,
                                                       const int* __restrict__ rowptr,
                                                       const int2* __restrict__ edata,
                                                       int N,
                                                       const float* __restrict__ bias,
                                                       const float* __restrict__ Wn,
                                                       float* __restrict__ out) {
    __shared__ float Wsh[HID * HID];
    __shared__ float hs[BROWS][36];
    int tid = threadIdx.x;
    int b = blockIdx.x;
    *(float4*)&Wsh[tid * 4] = ((const float4*)Wn)[tid];
    int g = tid >> 3, l = tid & 7;
    int row = b * BROWS + g;
    float4 acc = {0.f,0.f,0.f,0.f};
    if (row < N) {
        int e0 = rowptr[row];
        int e1 = rowptr[row + 1];
        acc = spmm_row_f4(sup4, edata, e0, e1, l);
    }
    float4 b4 = ((const float4*)bias)[l];
    float4 h;
    h.x = selu_f(acc.x) + b4.x;
    h.y = selu_f(acc.y) + b4.y;
    h.z = selu_f(acc.z) + b4.z;
    h.w = selu_f(acc.w) + b4.w;
    *(float4*)&hs[g][l * 4] = h;
    __syncthreads();
    int d = tid & 31;
    #pragma unroll
    for (int k = 0; k < 4; ++k) {
        int rl = (tid >> 5) + k * 8;
        int rrow = b * BROWS + rl;
        float o = 0.f;
        #pragma unroll
        for (int j = 0; j < HID; ++j) o += hs[rl][j] * Wsh[j * HID + d];
        if (rrow < N) out[(size_t)rrow * HID + d] = o;
    }
}

__global__ __launch_bounds__(256) void spmm_final_kernel(const float4* __restrict__ sup4,
                                                         const int* __restrict__ rowptr,
                                                         const int2* __restrict__ edata,
                                                         int N,
                                                         const float* __restrict__ bias,
                                                         const float* __restrict__ cw0,
                                                         const float* __restrict__ cb0,
                                                         const float* __restrict__ cw1,
                                                         const float* __restrict__ cb1,
                                                         float* __restrict__ out) {
    __shared__ float hs[BROWS][36];
    int tid = threadIdx.x;
    int b = blockIdx.x;
    int g = tid >> 3, l = tid & 7;
    int row = b * BROWS + g;
    float4 acc = {0.f,0.f,0.f,0.f};
    if (row < N) {
        int e0 = rowptr[row];
        int e1 = rowptr[row + 1];
        acc = spmm_row_f4(sup4, edata, e0, e1, l);
    }
    float4 b4 = ((const float4*)bias)[l];
    float4 h;
    h.x = selu_f(acc.x) + b4.x;
    h.y = selu_f(acc.y) + b4.y;
    h.z = selu_f(acc.z) + b4.z;
    h.w = selu_f(acc.w) + b4.w;
    *(float4*)&hs[g][l * 4] = h;
    __syncthreads();
    if (tid < BROWS * 5) {
        int rl = tid / 5, t = tid % 5;
        int rrow = b * BROWS + rl;
        if (rrow < N) {
            if (t < 2) {
                float o = cb0[t];
                #pragma unroll
                for (int j = 0; j < HID; ++j) o += hs[rl][j] * cw0[t * HID + j];
                out[(size_t)rrow * 2 + t] = o;
            } else {
                int c = t - 2;
                float o = cb1[c];
                #pragma unroll
                for (int j = 0; j < HID; ++j) o += hs[rl][j] * cw1[c * HID + j];
                out[(size_t)N * 2 + (size_t)rrow * 3 + c] = o;
            }
        }
    }
}

// ---------------- launch ----------------

extern "C" void kernel_launch(void* const* d_in, const int* in_sizes, int n_in,
                              void* d_out, int out_size, void* d_ws, size_t ws_size,
                              hipStream_t stream) {
    const float* x        = (const float*)d_in[0];
    const int*   adj_rows = (const int*)d_in[1];
    const int*   adj_cols = (const int*)d_in[2];
    const float* adj_vals = (const float*)d_in[3];
    const float* w1 = (const float*)d_in[4];
    const float* b1 = (const float*)d_in[5];
    const float* w2 = (const float*)d_in[6];
    const float* b2 = (const float*)d_in[7];
    const float* w3 = (const float*)d_in[8];
    const float* b3 = (const float*)d_in[9];
    const float* cw0 = (const float*)d_in[10];
    const float* cb0 = (const float*)d_in[11];
    const float* cw1 = (const float*)d_in[12];
    const float* cb1 = (const float*)d_in[13];

    int N = in_sizes[0] / IN_DIM;   // 50000
    int E = in_sizes[1];            // 1.6M
    int NB = (N + BROWS - 1) >> BSHIFT;      // 1563 buckets
    int M = NB * NBLK;                        // ~100K
    int nchunk = (E + NBLK - 1) / NBLK;
    int nb1 = (M + 1023) / 1024;              // 98 <= 128

    char* p = (char*)d_ws;
    float* s_a   = (float*)p; p += (size_t)N * HID * sizeof(float);
    float* s_b   = (float*)p; p += (size_t)N * HID * sizeof(float);
    int2*  edata = (int2*)p;  p += (size_t)E * sizeof(int2);
    int*   counts   = (int*)p; p += (size_t)M * sizeof(int);
    int*   offs     = (int*)p; p += (size_t)M * sizeof(int);
    int*   rowptr   = (int*)p; p += (size_t)(NB * BROWS + 1) * sizeof(int);
    int*   partials = (int*)p; p += 128 * sizeof(int);

    // Build bucket-partitioned, row-sorted edge list + rowptr (once; reused 3x)
    part_hist<<<NBLK, 1024, 0, stream>>>(adj_rows, E, NB, nchunk, counts);
    scan1_kernel<<<nb1, 1024, 0, stream>>>(counts, M, offs, partials);
    scan2_kernel<<<1, 128, 0, stream>>>(partials, nb1);
    scan3_kernel<<<nb1, 1024, 0, stream>>>(offs, partials, M);
    part_scatter<<<NBLK, 1024, 0, stream>>>(adj_rows, adj_cols, adj_vals, E, NB, nchunk,
                                            offs, edata);
    bucket_sort<<<NB, 256, 0, stream>>>(edata, offs, E, NB, rowptr);

    // Layer pipeline
    gemm1_kernel<<<(N + 31) / 32, 256, 0, stream>>>(x, w1, s_a, N);
    spmm_mid_kernel<<<NB, 256, 0, stream>>>((const float4*)s_a, rowptr, edata, N, b1, w2, s_b);
    spmm_mid_kernel<<<NB, 256, 0, stream>>>((const float4*)s_b, rowptr, edata, N, b2, w3, s_a);
    spmm_final_kernel<<<NB, 256, 0, stream>>>((const float4*)s_a, rowptr, edata, N,
                                              b3, cw0, cb0, cw1, cb1, (float*)d_out);
}

// Round 5
// 475.431 us; speedup vs baseline: 2.7501x; 1.0435x over previous
//
#include <hip/hip_runtime.h>

#define IN_DIM 1024
#define HID 32
#define BSHIFT 5            // 32 rows per bucket
#define BROWS 32
#define MAXB 1600           // max buckets (N up to 51200)
#define NBLK 128            // partition blocks (full-CU coverage; 8-edge=64B segments)
#define SORT_CAP 4096       // bucket sort LDS capacity (edges)

__device__ __forceinline__ float selu_f(float x) {
    const float scale = 1.0507009873554805f;
    const float alpha = 1.6732632423543772f;
    return x > 0.f ? scale * x : scale * alpha * (expf(x) - 1.f);
}

// ---------------- Bucket partition ----------------
// counts layout [blk][b] (coalesced writeout); logical scan order is (b, blk).

__global__ __launch_bounds__(1024) void part_hist(const int* __restrict__ rows, int E, int NB,
                                                  int nchunk, int* __restrict__ counts) {
    __shared__ int lh[MAXB];
    int tid = threadIdx.x, blk = blockIdx.x;
    for (int b = tid; b < NB; b += 1024) lh[b] = 0;
    __syncthreads();
    int base = blk * nchunk;
    int end = base + nchunk; if (end > E) end = E;
    for (int i = base + tid; i < end; i += 1024)
        atomicAdd(&lh[rows[i] >> BSHIFT], 1);
    __syncthreads();
    for (int b = tid; b < NB; b += 1024) counts[blk * NB + b] = lh[b];  // coalesced
}

// scan1: exclusive scan over logical index i=(b*NBLK+blk); reads transposed counts.
__global__ __launch_bounds__(1024) void scan1_kernel(const int* __restrict__ counts, int M,
                                                     int NB,
                                                     int* __restrict__ offs,
                                                     int* __restrict__ partials) {
    __shared__ int s[1024];
    int tid = threadIdx.x;
    int i = blockIdx.x * 1024 + tid;
    int v = 0;
    if (i < M) {
        int b = i >> 7;            // i / NBLK  (NBLK=128)
        int blk = i & (NBLK - 1);
        v = counts[blk * NB + b];
    }
    s[tid] = v;
    __syncthreads();
    for (int off = 1; off < 1024; off <<= 1) {
        int t = (tid >= off) ? s[tid - off] : 0;
        __syncthreads();
        s[tid] += t;
        __syncthreads();
    }
    if (i < M) offs[i] = s[tid] - v;            // exclusive within block
    if (tid == 1023) partials[blockIdx.x] = s[tid];
}

// scan2+3 fused: each block self-scans the (<=256) block totals in LDS, adds its prefix.
__global__ __launch_bounds__(1024) void scan_fix_kernel(int* __restrict__ offs,
                                                        const int* __restrict__ partials,
                                                        int M, int nb1) {
    __shared__ int s[256];
    int tid = threadIdx.x;
    if (tid < 256) s[tid] = (tid < nb1) ? partials[tid] : 0;
    __syncthreads();
    for (int off = 1; off < 256; off <<= 1) {
        int t = 0;
        if (tid < 256 && tid >= off) t = s[tid - off];
        __syncthreads();
        if (tid < 256) s[tid] += t;
        __syncthreads();
    }
    int myoff = (blockIdx.x == 0) ? 0 : s[blockIdx.x - 1];
    int i = blockIdx.x * 1024 + tid;
    if (i < M) offs[i] += myoff;
}

// LDS-cursor scatter into bucket segments (64B-granular, no global atomics)
__global__ __launch_bounds__(1024) void part_scatter(const int* __restrict__ rows,
                                                     const int* __restrict__ cols,
                                                     const float* __restrict__ vals, int E,
                                                     int NB, int nchunk,
                                                     const int* __restrict__ offs,
                                                     int2* __restrict__ edata) {
    __shared__ int lc[MAXB];
    int tid = threadIdx.x, blk = blockIdx.x;
    for (int b = tid; b < NB; b += 1024) lc[b] = offs[b * NBLK + blk];
    __syncthreads();
    int base = blk * nchunk;
    int end = base + nchunk; if (end > E) end = E;
    for (int i = base + tid; i < end; i += 1024) {
        int r = rows[i];
        int b = r >> BSHIFT;
        int p = atomicAdd(&lc[b], 1);
        int2 pr;
        pr.x = ((r & (BROWS - 1)) << 18) | cols[i];   // rl:5b | col:18b
        pr.y = __float_as_int(vals[i]);
        edata[p] = pr;
    }
}

// In-place counting sort of each bucket by local row; emits rowptr.
__global__ __launch_bounds__(256) void bucket_sort(int2* __restrict__ edata,
                                                   const int* __restrict__ offs,
                                                   int E, int NB,
                                                   int* __restrict__ rowptr) {
    __shared__ int2 stage[SORT_CAP];
    __shared__ int cnt[32], startsh[32], cur[32];
    int b = blockIdx.x, tid = threadIdx.x;
    int s0 = offs[b * NBLK];
    int s1 = (b + 1 < NB) ? offs[(b + 1) * NBLK] : E;
    int n = s1 - s0;
    if (tid < 32) cnt[tid] = 0;
    __syncthreads();
    for (int i = tid; i < n; i += 256) {
        int2 pr = edata[s0 + i];
        stage[i] = pr;
        atomicAdd(&cnt[pr.x >> 18], 1);
    }
    __syncthreads();
    if (tid == 0) {
        int run = 0;
        #pragma unroll
        for (int k = 0; k < 32; ++k) { startsh[k] = run; run += cnt[k]; }
    }
    __syncthreads();
    if (tid < 32) {
        cur[tid] = startsh[tid];
        rowptr[b * BROWS + tid] = s0 + startsh[tid];
    }
    __syncthreads();
    for (int i = tid; i < n; i += 256) {
        int2 pr = stage[i];
        int p = atomicAdd(&cur[pr.x >> 18], 1);
        edata[s0 + p] = pr;     // within this bucket's ~8KB window (L2-resident)
    }
}

// ---------------- GEMM1: support1 = x @ w1 ----------------

#define XS_LD 132

__global__ __launch_bounds__(256) void gemm1_kernel(const float* __restrict__ x,
                                                    const float* __restrict__ w,
                                                    float* __restrict__ out, int N) {
    __shared__ float xs[32 * XS_LD];
    __shared__ float ws[128 * HID];
    int tid = threadIdx.x;
    int r  = tid >> 3;
    int d0 = (tid & 7) * 4;
    int row0 = blockIdx.x * 32;

    float4 acc = make_float4(0.f, 0.f, 0.f, 0.f);

    for (int kc = 0; kc < IN_DIM; kc += 128) {
        #pragma unroll
        for (int j = 0; j < 4; ++j) {
            int linear = tid + j * 256;
            int rr = linear >> 5;
            int cc = linear & 31;
            int grow = row0 + rr;
            if (grow > N - 1) grow = N - 1;
            float4 t = *(const float4*)&x[(size_t)grow * IN_DIM + kc + cc * 4];
            *(float4*)&xs[rr * XS_LD + cc * 4] = t;
        }
        #pragma unroll
        for (int j = 0; j < 4; ++j) {
            int linear = tid + j * 256;
            int kk = linear >> 3;
            int dd = (linear & 7) * 4;
            float4 t = *(const float4*)&w[(kc + kk) * HID + dd];
            *(float4*)&ws[kk * HID + dd] = t;
        }
        __syncthreads();
        #pragma unroll
        for (int k4 = 0; k4 < 32; ++k4) {
            float4 xv = *(const float4*)&xs[r * XS_LD + k4 * 4];
            float4 wv0 = *(const float4*)&ws[(k4 * 4 + 0) * HID + d0];
            acc.x += xv.x * wv0.x; acc.y += xv.x * wv0.y; acc.z += xv.x * wv0.z; acc.w += xv.x * wv0.w;
            float4 wv1 = *(const float4*)&ws[(k4 * 4 + 1) * HID + d0];
            acc.x += xv.y * wv1.x; acc.y += xv.y * wv1.y; acc.z += xv.y * wv1.z; acc.w += xv.y * wv1.w;
            float4 wv2 = *(const float4*)&ws[(k4 * 4 + 2) * HID + d0];
            acc.x += xv.z * wv2.x; acc.y += xv.z * wv2.y; acc.z += xv.z * wv2.z; acc.w += xv.z * wv2.w;
            float4 wv3 = *(const float4*)&ws[(k4 * 4 + 3) * HID + d0];
            acc.x += xv.w * wv3.x; acc.y += xv.w * wv3.y; acc.z += xv.w * wv3.z; acc.w += xv.w * wv3.w;
        }
        __syncthreads();
    }
    int grow = row0 + r;
    if (grow < N) *(float4*)&out[(size_t)grow * HID + d0] = acc;
}

// ---------------- SpMM: 8-lane group per row, float4 register accumulator ----------------

__device__ __forceinline__ float4 spmm_row_f4(const float4* __restrict__ sup4,
                                              const int2* __restrict__ edata,
                                              int e0, int e1, int l) {
    float4 a0 = {0.f,0.f,0.f,0.f}, a1 = a0, a2 = a0, a3 = a0;
    int e = e0;
    for (; e + 8 <= e1; e += 8) {          // 8 gathers in flight per group
        int2 m0 = edata[e],   m1 = edata[e+1], m2 = edata[e+2], m3 = edata[e+3];
        int2 m4 = edata[e+4], m5 = edata[e+5], m6 = edata[e+6], m7 = edata[e+7];
        float4 g0 = sup4[(size_t)(m0.x & 0x3FFFF) * 8 + l];
        float4 g1 = sup4[(size_t)(m1.x & 0x3FFFF) * 8 + l];
        float4 g2 = sup4[(size_t)(m2.x & 0x3FFFF) * 8 + l];
        float4 g3 = sup4[(size_t)(m3.x & 0x3FFFF) * 8 + l];
        float4 g4 = sup4[(size_t)(m4.x & 0x3FFFF) * 8 + l];
        float4 g5 = sup4[(size_t)(m5.x & 0x3FFFF) * 8 + l];
        float4 g6 = sup4[(size_t)(m6.x & 0x3FFFF) * 8 + l];
        float4 g7 = sup4[(size_t)(m7.x & 0x3FFFF) * 8 + l];
        float v0 = __int_as_float(m0.y), v1 = __int_as_float(m1.y);
        float v2 = __int_as_float(m2.y), v3 = __int_as_float(m3.y);
        float v4 = __int_as_float(m4.y), v5 = __int_as_float(m5.y);
        float v6 = __int_as_float(m6.y), v7 = __int_as_float(m7.y);
        a0.x += v0*g0.x; a0.y += v0*g0.y; a0.z += v0*g0.z; a0.w += v0*g0.w;
        a1.x += v1*g1.x; a1.y += v1*g1.y; a1.z += v1*g1.z; a1.w += v1*g1.w;
        a2.x += v2*g2.x; a2.y += v2*g2.y; a2.z += v2*g2.z; a2.w += v2*g2.w;
        a3.x += v3*g3.x; a3.y += v3*g3.y; a3.z += v3*g3.z; a3.w += v3*g3.w;
        a0.x += v4*g4.x; a0.y += v4*g4.y; a0.z += v4*g4.z; a0.w += v4*g4.w;
        a1.x += v5*g5.x; a1.y += v5*g5.y; a1.z += v5*g5.z; a1.w += v5*g5.w;
        a2.x += v6*g6.x; a2.y += v6*g6.y; a2.z += v6*g6.z; a2.w += v6*g6.w;
        a3.x += v7*g7.x; a3.y += v7*g7.y; a3.z += v7*g7.z; a3.w += v7*g7.w;
    }
    for (; e < e1; ++e) {
        int2 m0 = edata[e];
        float4 g0 = sup4[(size_t)(m0.x & 0x3FFFF) * 8 + l];
        float v0 = __int_as_float(m0.y);
        a0.x += v0*g0.x; a0.y += v0*g0.y; a0.z += v0*g0.z; a0.w += v0*g0.w;
    }
    a0.x += a1.x + a2.x + a3.x;
    a0.y += a1.y + a2.y + a3.y;
    a0.z += a1.z + a2.z + a3.z;
    a0.w += a1.w + a2.w + a3.w;
    return a0;
}

__global__ __launch_bounds__(256) void spmm_mid_kernel(const float4* __restrict__ sup4,
                                                       const int* __restrict__ rowptr,
                                                       const int2* __restrict__ edata,
                                                       int N,
                                                       const float* __restrict__ bias,
                                                       const float* __restrict__ Wn,
                                                       float* __restrict__ out) {
    __shared__ float Wsh[HID * HID];
    __shared__ float hs[BROWS][36];
    int tid = threadIdx.x;
    int b = blockIdx.x;
    *(float4*)&Wsh[tid * 4] = ((const float4*)Wn)[tid];
    int g = tid >> 3, l = tid & 7;
    int row = b * BROWS + g;
    float4 acc = {0.f,0.f,0.f,0.f};
    if (row < N) {
        int e0 = rowptr[row];
        int e1 = rowptr[row + 1];
        acc = spmm_row_f4(sup4, edata, e0, e1, l);
    }
    float4 b4 = ((const float4*)bias)[l];
    float4 h;
    h.x = selu_f(acc.x) + b4.x;
    h.y = selu_f(acc.y) + b4.y;
    h.z = selu_f(acc.z) + b4.z;
    h.w = selu_f(acc.w) + b4.w;
    *(float4*)&hs[g][l * 4] = h;
    __syncthreads();
    int d = tid & 31;
    #pragma unroll
    for (int k = 0; k < 4; ++k) {
        int rl = (tid >> 5) + k * 8;
        int rrow = b * BROWS + rl;
        float o = 0.f;
        #pragma unroll
        for (int j = 0; j < HID; ++j) o += hs[rl][j] * Wsh[j * HID + d];
        if (rrow < N) out[(size_t)rrow * HID + d] = o;
    }
}

__global__ __launch_bounds__(256) void spmm_final_kernel(const float4* __restrict__ sup4,
                                                         const int* __restrict__ rowptr,
                                                         const int2* __restrict__ edata,
                                                         int N,
                                                         const float* __restrict__ bias,
                                                         const float* __restrict__ cw0,
                                                         const float* __restrict__ cb0,
                                                         const float* __restrict__ cw1,
                                                         const float* __restrict__ cb1,
                                                         float* __restrict__ out) {
    __shared__ float hs[BROWS][36];
    int tid = threadIdx.x;
    int b = blockIdx.x;
    int g = tid >> 3, l = tid & 7;
    int row = b * BROWS + g;
    float4 acc = {0.f,0.f,0.f,0.f};
    if (row < N) {
        int e0 = rowptr[row];
        int e1 = rowptr[row + 1];
        acc = spmm_row_f4(sup4, edata, e0, e1, l);
    }
    float4 b4 = ((const float4*)bias)[l];
    float4 h;
    h.x = selu_f(acc.x) + b4.x;
    h.y = selu_f(acc.y) + b4.y;
    h.z = selu_f(acc.z) + b4.z;
    h.w = selu_f(acc.w) + b4.w;
    *(float4*)&hs[g][l * 4] = h;
    __syncthreads();
    if (tid < BROWS * 5) {
        int rl = tid / 5, t = tid % 5;
        int rrow = b * BROWS + rl;
        if (rrow < N) {
            if (t < 2) {
                float o = cb0[t];
                #pragma unroll
                for (int j = 0; j < HID; ++j) o += hs[rl][j] * cw0[t * HID + j];
                out[(size_t)rrow * 2 + t] = o;
            } else {
                int c = t - 2;
                float o = cb1[c];
                #pragma unroll
                for (int j = 0; j < HID; ++j) o += hs[rl][j] * cw1[c * HID + j];
                out[(size_t)N * 2 + (size_t)rrow * 3 + c] = o;
            }
        }
    }
}

// ---------------- launch ----------------

extern "C" void kernel_launch(void* const* d_in, const int* in_sizes, int n_in,
                              void* d_out, int out_size, void* d_ws, size_t ws_size,
                              hipStream_t stream) {
    const float* x        = (const float*)d_in[0];
    const int*   adj_rows = (const int*)d_in[1];
    const int*   adj_cols = (const int*)d_in[2];
    const float* adj_vals = (const float*)d_in[3];
    const float* w1 = (const float*)d_in[4];
    const float* b1 = (const float*)d_in[5];
    const float* w2 = (const float*)d_in[6];
    const float* b2 = (const float*)d_in[7];
    const float* w3 = (const float*)d_in[8];
    const float* b3 = (const float*)d_in[9];
    const float* cw0 = (const float*)d_in[10];
    const float* cb0 = (const float*)d_in[11];
    const float* cw1 = (const float*)d_in[12];
    const float* cb1 = (const float*)d_in[13];

    int N = in_sizes[0] / IN_DIM;   // 50000
    int E = in_sizes[1];            // 1.6M
    int NB = (N + BROWS - 1) >> BSHIFT;      // 1563 buckets
    int M = NB * NBLK;                        // ~200K
    int nchunk = (E + NBLK - 1) / NBLK;       // 12500
    int nb1 = (M + 1023) / 1024;              // 196 <= 256

    char* p = (char*)d_ws;
    float* s_a   = (float*)p; p += (size_t)N * HID * sizeof(float);
    float* s_b   = (float*)p; p += (size_t)N * HID * sizeof(float);
    int2*  edata = (int2*)p;  p += (size_t)E * sizeof(int2);
    int*   counts   = (int*)p; p += (size_t)M * sizeof(int);
    int*   offs     = (int*)p; p += (size_t)M * sizeof(int);
    int*   rowptr   = (int*)p; p += (size_t)(NB * BROWS + 1) * sizeof(int);
    int*   partials = (int*)p; p += 256 * sizeof(int);

    // Build bucket-partitioned, row-sorted edge list + rowptr (once; reused 3x)
    part_hist<<<NBLK, 1024, 0, stream>>>(adj_rows, E, NB, nchunk, counts);
    scan1_kernel<<<nb1, 1024, 0, stream>>>(counts, M, NB, offs, partials);
    scan_fix_kernel<<<nb1, 1024, 0, stream>>>(offs, partials, M, nb1);
    part_scatter<<<NBLK, 1024, 0, stream>>>(adj_rows, adj_cols, adj_vals, E, NB, nchunk,
                                            offs, edata);
    bucket_sort<<<NB, 256, 0, stream>>>(edata, offs, E, NB, rowptr);

    // Layer pipeline
    gemm1_kernel<<<(N + 31) / 32, 256, 0, stream>>>(x, w1, s_a, N);
    spmm_mid_kernel<<<NB, 256, 0, stream>>>((const float4*)s_a, rowptr, edata, N, b1, w2, s_b);
    spmm_mid_kernel<<<NB, 256, 0, stream>>>((const float4*)s_b, rowptr, edata, N, b2, w3, s_a);
    spmm_final_kernel<<<NB, 256, 0, stream>>>((const float4*)s_a, rowptr, edata, N,
                                              b3, cw0, cb0, cw1, cb1, (float*)d_out);
}

// Round 6
// 475.182 us; speedup vs baseline: 2.7515x; 1.0005x over previous
//
#include <hip/hip_runtime.h>

#define IN_DIM 1024
#define HID 32
#define BSHIFT 5            // 32 rows per bucket
#define BROWS 32
#define MAXB 1600           // max buckets (N up to 51200)
#define NBLK 128            // partition blocks
#define SORT_CAP 4096       // bucket sort LDS capacity (edges)

__device__ __forceinline__ float selu_f(float x) {
    const float scale = 1.0507009873554805f;
    const float alpha = 1.6732632423543772f;
    return x > 0.f ? scale * x : scale * alpha * (expf(x) - 1.f);
}

// ---------------- Bucket partition ----------------

__global__ __launch_bounds__(1024) void part_hist(const int* __restrict__ rows, int E, int NB,
                                                  int nchunk, int* __restrict__ counts) {
    __shared__ int lh[MAXB];
    int tid = threadIdx.x, blk = blockIdx.x;
    for (int b = tid; b < NB; b += 1024) lh[b] = 0;
    __syncthreads();
    int base = blk * nchunk;
    int end = base + nchunk; if (end > E) end = E;
    for (int i = base + tid; i < end; i += 1024)
        atomicAdd(&lh[rows[i] >> BSHIFT], 1);
    __syncthreads();
    for (int b = tid; b < NB; b += 1024) counts[blk * NB + b] = lh[b];  // coalesced
}

__global__ __launch_bounds__(1024) void scan1_kernel(const int* __restrict__ counts, int M,
                                                     int NB,
                                                     int* __restrict__ offs,
                                                     int* __restrict__ partials) {
    __shared__ int s[1024];
    int tid = threadIdx.x;
    int i = blockIdx.x * 1024 + tid;
    int v = 0;
    if (i < M) {
        int b = i >> 7;            // i / NBLK  (NBLK=128)
        int blk = i & (NBLK - 1);
        v = counts[blk * NB + b];
    }
    s[tid] = v;
    __syncthreads();
    for (int off = 1; off < 1024; off <<= 1) {
        int t = (tid >= off) ? s[tid - off] : 0;
        __syncthreads();
        s[tid] += t;
        __syncthreads();
    }
    if (i < M) offs[i] = s[tid] - v;
    if (tid == 1023) partials[blockIdx.x] = s[tid];
}

__global__ __launch_bounds__(1024) void scan_fix_kernel(int* __restrict__ offs,
                                                        const int* __restrict__ partials,
                                                        int M, int nb1) {
    __shared__ int s[256];
    int tid = threadIdx.x;
    if (tid < 256) s[tid] = (tid < nb1) ? partials[tid] : 0;
    __syncthreads();
    for (int off = 1; off < 256; off <<= 1) {
        int t = 0;
        if (tid < 256 && tid >= off) t = s[tid - off];
        __syncthreads();
        if (tid < 256) s[tid] += t;
        __syncthreads();
    }
    int myoff = (blockIdx.x == 0) ? 0 : s[blockIdx.x - 1];
    int i = blockIdx.x * 1024 + tid;
    if (i < M) offs[i] += myoff;
}

__global__ __launch_bounds__(1024) void part_scatter(const int* __restrict__ rows,
                                                     const int* __restrict__ cols,
                                                     const float* __restrict__ vals, int E,
                                                     int NB, int nchunk,
                                                     const int* __restrict__ offs,
                                                     int2* __restrict__ edata) {
    __shared__ int lc[MAXB];
    int tid = threadIdx.x, blk = blockIdx.x;
    for (int b = tid; b < NB; b += 1024) lc[b] = offs[b * NBLK + blk];
    __syncthreads();
    int base = blk * nchunk;
    int end = base + nchunk; if (end > E) end = E;
    for (int i = base + tid; i < end; i += 1024) {
        int r = rows[i];
        int b = r >> BSHIFT;
        int p = atomicAdd(&lc[b], 1);
        int2 pr;
        pr.x = ((r & (BROWS - 1)) << 18) | cols[i];   // rl:5b | col:18b
        pr.y = __float_as_int(vals[i]);
        edata[p] = pr;
    }
}

__global__ __launch_bounds__(256) void bucket_sort(int2* __restrict__ edata,
                                                   const int* __restrict__ offs,
                                                   int E, int NB,
                                                   int* __restrict__ rowptr) {
    __shared__ int2 stage[SORT_CAP];
    __shared__ int cnt[32], startsh[32], cur[32];
    int b = blockIdx.x, tid = threadIdx.x;
    int s0 = offs[b * NBLK];
    int s1 = (b + 1 < NB) ? offs[(b + 1) * NBLK] : E;
    int n = s1 - s0;
    if (tid < 32) cnt[tid] = 0;
    __syncthreads();
    for (int i = tid; i < n; i += 256) {
        int2 pr = edata[s0 + i];
        stage[i] = pr;
        atomicAdd(&cnt[pr.x >> 18], 1);
    }
    __syncthreads();
    if (tid == 0) {
        int run = 0;
        #pragma unroll
        for (int k = 0; k < 32; ++k) { startsh[k] = run; run += cnt[k]; }
    }
    __syncthreads();
    if (tid < 32) {
        cur[tid] = startsh[tid];
        rowptr[b * BROWS + tid] = s0 + startsh[tid];
    }
    __syncthreads();
    for (int i = tid; i < n; i += 256) {
        int2 pr = stage[i];
        int p = atomicAdd(&cur[pr.x >> 18], 1);
        edata[s0 + p] = pr;
    }
}

// ---------------- GEMM1 v2: register-tiled, 4 rows x 4 cols per thread ----------------
// BR=128, BK=64. Per k4-iter: 8 ds_read_b128 per 8192 wave-FLOPs (2.56x fewer LDS
// instrs than v1). XS_LD=68: row stride = 4 banks -> 8 rt-rows hit disjoint bank
// quads; ct-broadcast free. wv at banks ct*4: disjoint, rt-broadcast free.

#define BR 128
#define BK 64
#define XS_LD (BK + 4)

__global__ __launch_bounds__(256) void gemm1_kernel(const float* __restrict__ x,
                                                    const float* __restrict__ w,
                                                    float* __restrict__ out, int N) {
    __shared__ float xs[BR * XS_LD];   // 34.8 KB
    __shared__ float ws[BK * HID];     // 8 KB
    int tid = threadIdx.x;
    int ct = tid & 7;          // 8 col-groups
    int d0 = ct * 4;
    int rt = tid >> 3;         // 0..31
    int row0 = blockIdx.x * BR;

    float4 acc0 = {0,0,0,0}, acc1 = {0,0,0,0}, acc2 = {0,0,0,0}, acc3 = {0,0,0,0};

    for (int kc = 0; kc < IN_DIM; kc += BK) {
        // stage x: 128 rows x 64 k = 2048 float4, 8 per thread, coalesced
        #pragma unroll
        for (int j = 0; j < 8; ++j) {
            int linear = tid + j * 256;
            int rr = linear >> 4;          // 0..127
            int cc = linear & 15;          // f4 idx within row
            int grow = row0 + rr;
            if (grow > N - 1) grow = N - 1;
            float4 t = *(const float4*)&x[(size_t)grow * IN_DIM + kc + cc * 4];
            *(float4*)&xs[rr * XS_LD + cc * 4] = t;
        }
        // stage w: 64 k x 32 d = 512 float4, 2 per thread
        #pragma unroll
        for (int j = 0; j < 2; ++j) {
            int linear = tid + j * 256;
            int kk = linear >> 3;
            int dd = (linear & 7) * 4;
            float4 t = *(const float4*)&w[(kc + kk) * HID + dd];
            *(float4*)&ws[kk * HID + dd] = t;
        }
        __syncthreads();
        #pragma unroll
        for (int k4 = 0; k4 < BK / 4; ++k4) {
            float4 wv0 = *(const float4*)&ws[(k4 * 4 + 0) * HID + d0];
            float4 wv1 = *(const float4*)&ws[(k4 * 4 + 1) * HID + d0];
            float4 wv2 = *(const float4*)&ws[(k4 * 4 + 2) * HID + d0];
            float4 wv3 = *(const float4*)&ws[(k4 * 4 + 3) * HID + d0];
            float4 xv;
            #define GEMM_STEP(ACC, I) \
                xv = *(const float4*)&xs[(rt + 32 * I) * XS_LD + k4 * 4]; \
                ACC.x += xv.x * wv0.x; ACC.y += xv.x * wv0.y; ACC.z += xv.x * wv0.z; ACC.w += xv.x * wv0.w; \
                ACC.x += xv.y * wv1.x; ACC.y += xv.y * wv1.y; ACC.z += xv.y * wv1.z; ACC.w += xv.y * wv1.w; \
                ACC.x += xv.z * wv2.x; ACC.y += xv.z * wv2.y; ACC.z += xv.z * wv2.z; ACC.w += xv.z * wv2.w; \
                ACC.x += xv.w * wv3.x; ACC.y += xv.w * wv3.y; ACC.z += xv.w * wv3.z; ACC.w += xv.w * wv3.w;
            GEMM_STEP(acc0, 0)
            GEMM_STEP(acc1, 1)
            GEMM_STEP(acc2, 2)
            GEMM_STEP(acc3, 3)
            #undef GEMM_STEP
        }
        __syncthreads();
    }
    {
        int grow = row0 + rt;
        if (grow < N)       *(float4*)&out[(size_t)grow * HID + d0] = acc0;
        grow += 32;
        if (grow < N)       *(float4*)&out[(size_t)grow * HID + d0] = acc1;
        grow += 32;
        if (grow < N)       *(float4*)&out[(size_t)grow * HID + d0] = acc2;
        grow += 32;
        if (grow < N)       *(float4*)&out[(size_t)grow * HID + d0] = acc3;
    }
}

// ---------------- SpMM: 8-lane group per row, float4 register accumulator ----------------

__device__ __forceinline__ float4 spmm_row_f4(const float4* __restrict__ sup4,
                                              const int2* __restrict__ edata,
                                              int e0, int e1, int l) {
    float4 a0 = {0.f,0.f,0.f,0.f}, a1 = a0, a2 = a0, a3 = a0;
    int e = e0;
    for (; e + 8 <= e1; e += 8) {
        int2 m0 = edata[e],   m1 = edata[e+1], m2 = edata[e+2], m3 = edata[e+3];
        int2 m4 = edata[e+4], m5 = edata[e+5], m6 = edata[e+6], m7 = edata[e+7];
        float4 g0 = sup4[(size_t)(m0.x & 0x3FFFF) * 8 + l];
        float4 g1 = sup4[(size_t)(m1.x & 0x3FFFF) * 8 + l];
        float4 g2 = sup4[(size_t)(m2.x & 0x3FFFF) * 8 + l];
        float4 g3 = sup4[(size_t)(m3.x & 0x3FFFF) * 8 + l];
        float4 g4 = sup4[(size_t)(m4.x & 0x3FFFF) * 8 + l];
        float4 g5 = sup4[(size_t)(m5.x & 0x3FFFF) * 8 + l];
        float4 g6 = sup4[(size_t)(m6.x & 0x3FFFF) * 8 + l];
        float4 g7 = sup4[(size_t)(m7.x & 0x3FFFF) * 8 + l];
        float v0 = __int_as_float(m0.y), v1 = __int_as_float(m1.y);
        float v2 = __int_as_float(m2.y), v3 = __int_as_float(m3.y);
        float v4 = __int_as_float(m4.y), v5 = __int_as_float(m5.y);
        float v6 = __int_as_float(m6.y), v7 = __int_as_float(m7.y);
        a0.x += v0*g0.x; a0.y += v0*g0.y; a0.z += v0*g0.z; a0.w += v0*g0.w;
        a1.x += v1*g1.x; a1.y += v1*g1.y; a1.z += v1*g1.z; a1.w += v1*g1.w;
        a2.x += v2*g2.x; a2.y += v2*g2.y; a2.z += v2*g2.z; a2.w += v2*g2.w;
        a3.x += v3*g3.x; a3.y += v3*g3.y; a3.z += v3*g3.z; a3.w += v3*g3.w;
        a0.x += v4*g4.x; a0.y += v4*g4.y; a0.z += v4*g4.z; a0.w += v4*g4.w;
        a1.x += v5*g5.x; a1.y += v5*g5.y; a1.z += v5*g5.z; a1.w += v5*g5.w;
        a2.x += v6*g6.x; a2.y += v6*g6.y; a2.z += v6*g6.z; a2.w += v6*g6.w;
        a3.x += v7*g7.x; a3.y += v7*g7.y; a3.z += v7*g7.z; a3.w += v7*g7.w;
    }
    for (; e < e1; ++e) {
        int2 m0 = edata[e];
        float4 g0 = sup4[(size_t)(m0.x & 0x3FFFF) * 8 + l];
        float v0 = __int_as_float(m0.y);
        a0.x += v0*g0.x; a0.y += v0*g0.y; a0.z += v0*g0.z; a0.w += v0*g0.w;
    }
    a0.x += a1.x + a2.x + a3.x;
    a0.y += a1.y + a2.y + a3.y;
    a0.z += a1.z + a2.z + a3.z;
    a0.w += a1.w + a2.w + a3.w;
    return a0;
}

__global__ __launch_bounds__(256) void spmm_mid_kernel(const float4* __restrict__ sup4,
                                                       const int* __restrict__ rowptr,
                                                       const int2* __restrict__ edata,
                                                       int N,
                                                       const float* __restrict__ bias,
                                                       const float* __restrict__ Wn,
                                                       float* __restrict__ out) {
    __shared__ float Wsh[HID * HID];
    __shared__ float hs[BROWS][36];
    int tid = threadIdx.x;
    int b = blockIdx.x;
    *(float4*)&Wsh[tid * 4] = ((const float4*)Wn)[tid];
    int g = tid >> 3, l = tid & 7;
    int row = b * BROWS + g;
    float4 acc = {0.f,0.f,0.f,0.f};
    if (row < N) {
        int e0 = rowptr[row];
        int e1 = rowptr[row + 1];
        acc = spmm_row_f4(sup4, edata, e0, e1, l);
    }
    float4 b4 = ((const float4*)bias)[l];
    float4 h;
    h.x = selu_f(acc.x) + b4.x;
    h.y = selu_f(acc.y) + b4.y;
    h.z = selu_f(acc.z) + b4.z;
    h.w = selu_f(acc.w) + b4.w;
    *(float4*)&hs[g][l * 4] = h;
    __syncthreads();
    int d = tid & 31;
    #pragma unroll
    for (int k = 0; k < 4; ++k) {
        int rl = (tid >> 5) + k * 8;
        int rrow = b * BROWS + rl;
        float o = 0.f;
        #pragma unroll
        for (int j = 0; j < HID; ++j) o += hs[rl][j] * Wsh[j * HID + d];
        if (rrow < N) out[(size_t)rrow * HID + d] = o;
    }
}

__global__ __launch_bounds__(256) void spmm_final_kernel(const float4* __restrict__ sup4,
                                                         const int* __restrict__ rowptr,
                                                         const int2* __restrict__ edata,
                                                         int N,
                                                         const float* __restrict__ bias,
                                                         const float* __restrict__ cw0,
                                                         const float* __restrict__ cb0,
                                                         const float* __restrict__ cw1,
                                                         const float* __restrict__ cb1,
                                                         float* __restrict__ out) {
    __shared__ float hs[BROWS][36];
    int tid = threadIdx.x;
    int b = blockIdx.x;
    int g = tid >> 3, l = tid & 7;
    int row = b * BROWS + g;
    float4 acc = {0.f,0.f,0.f,0.f};
    if (row < N) {
        int e0 = rowptr[row];
        int e1 = rowptr[row + 1];
        acc = spmm_row_f4(sup4, edata, e0, e1, l);
    }
    float4 b4 = ((const float4*)bias)[l];
    float4 h;
    h.x = selu_f(acc.x) + b4.x;
    h.y = selu_f(acc.y) + b4.y;
    h.z = selu_f(acc.z) + b4.z;
    h.w = selu_f(acc.w) + b4.w;
    *(float4*)&hs[g][l * 4] = h;
    __syncthreads();
    if (tid < BROWS * 5) {
        int rl = tid / 5, t = tid % 5;
        int rrow = b * BROWS + rl;
        if (rrow < N) {
            if (t < 2) {
                float o = cb0[t];
                #pragma unroll
                for (int j = 0; j < HID; ++j) o += hs[rl][j] * cw0[t * HID + j];
                out[(size_t)rrow * 2 + t] = o;
            } else {
                int c = t - 2;
                float o = cb1[c];
                #pragma unroll
                for (int j = 0; j < HID; ++j) o += hs[rl][j] * cw1[c * HID + j];
                out[(size_t)N * 2 + (size_t)rrow * 3 + c] = o;
            }
        }
    }
}

// ---------------- launch ----------------

extern "C" void kernel_launch(void* const* d_in, const int* in_sizes, int n_in,
                              void* d_out, int out_size, void* d_ws, size_t ws_size,
                              hipStream_t stream) {
    const float* x        = (const float*)d_in[0];
    const int*   adj_rows = (const int*)d_in[1];
    const int*   adj_cols = (const int*)d_in[2];
    const float* adj_vals = (const float*)d_in[3];
    const float* w1 = (const float*)d_in[4];
    const float* b1 = (const float*)d_in[5];
    const float* w2 = (const float*)d_in[6];
    const float* b2 = (const float*)d_in[7];
    const float* w3 = (const float*)d_in[8];
    const float* b3 = (const float*)d_in[9];
    const float* cw0 = (const float*)d_in[10];
    const float* cb0 = (const float*)d_in[11];
    const float* cw1 = (const float*)d_in[12];
    const float* cb1 = (const float*)d_in[13];

    int N = in_sizes[0] / IN_DIM;   // 50000
    int E = in_sizes[1];            // 1.6M
    int NB = (N + BROWS - 1) >> BSHIFT;      // 1563 buckets
    int M = NB * NBLK;                        // ~200K
    int nchunk = (E + NBLK - 1) / NBLK;       // 12500
    int nb1 = (M + 1023) / 1024;              // 196 <= 256

    char* p = (char*)d_ws;
    float* s_a   = (float*)p; p += (size_t)N * HID * sizeof(float);
    float* s_b   = (float*)p; p += (size_t)N * HID * sizeof(float);
    int2*  edata = (int2*)p;  p += (size_t)E * sizeof(int2);
    int*   counts   = (int*)p; p += (size_t)M * sizeof(int);
    int*   offs     = (int*)p; p += (size_t)M * sizeof(int);
    int*   rowptr   = (int*)p; p += (size_t)(NB * BROWS + 1) * sizeof(int);
    int*   partials = (int*)p; p += 256 * sizeof(int);

    // Build bucket-partitioned, row-sorted edge list + rowptr (once; reused 3x)
    part_hist<<<NBLK, 1024, 0, stream>>>(adj_rows, E, NB, nchunk, counts);
    scan1_kernel<<<nb1, 1024, 0, stream>>>(counts, M, NB, offs, partials);
    scan_fix_kernel<<<nb1, 1024, 0, stream>>>(offs, partials, M, nb1);
    part_scatter<<<NBLK, 1024, 0, stream>>>(adj_rows, adj_cols, adj_vals, E, NB, nchunk,
                                            offs, edata);
    bucket_sort<<<NB, 256, 0, stream>>>(edata, offs, E, NB, rowptr);

    // Layer pipeline
    gemm1_kernel<<<(N + BR - 1) / BR, 256, 0, stream>>>(x, w1, s_a, N);
    spmm_mid_kernel<<<NB, 256, 0, stream>>>((const float4*)s_a, rowptr, edata, N, b1, w2, s_b);
    spmm_mid_kernel<<<NB, 256, 0, stream>>>((const float4*)s_b, rowptr, edata, N, b2, w3, s_a);
    spmm_final_kernel<<<NB, 256, 0, stream>>>((const float4*)s_a, rowptr, edata, N,
                                              b3, cw0, cb0, cw1, cb1, (float*)d_out);
}